// Round 1
// baseline (541.483 us; speedup 1.0000x reference)
//
#include <hip/hip_runtime.h>
#include <math.h>

// ToHyperSphere: x (B=65536, D=1024) fp32 -> out (B, D) fp32
// out[0]   = sqrt(sum x^2)                        (r)
// out[j]   = acos(x[j-1]/suffix_norm[j-1]), j=1..D-2
// out[D-1] = x[D-1] < 0 ? 2pi - phi[D-2] : phi[D-2]
// suffix_norm[j] = sqrt(sum_{k>=j} x[k]^2)
//
// ONE WAVE PER ROW: 64 lanes x 16 contiguous elements = 1024.
//  - suffix scan = 15 thread-local FMAs + 6-step __shfl_down wave scan
//    -> no LDS, no __syncthreads (old version paid 2 block barriers/row)
//  - 4 independent float4 loads per thread (4x memory-level parallelism
//    vs 1 load in the old 256-thread-per-row version)
//  - nontemporal float4 stores: output is write-only in the timed loop;
//    keep the 256MB input resident in L2/L3 instead of evicting it with
//    write-allocate traffic.
// Boundary element x[16t-1] comes from __shfl_up of the previous lane's
// last element (no inter-wave boundary exists anymore).

#define D_DIM 1024
#define TPB 256       // 4 waves per block
#define RPB 4         // rows per block (one per wave)
#define EPT 16        // elements per thread

typedef float v4f __attribute__((ext_vector_type(4)));

__device__ __forceinline__ float ang(float num, float den) {
    float r = num * rsqrtf(den);
    r = fminf(1.0f, fmaxf(-1.0f, r));
    return acosf(r);
}

__global__ __launch_bounds__(TPB) void tohypersphere_kernel(
    const float* __restrict__ x, float* __restrict__ out, int n_rows) {
    const int lane = threadIdx.x & 63;
    const int wv   = threadIdx.x >> 6;
    const int row  = blockIdx.x * RPB + wv;
    if (row >= n_rows) return;  // whole wave exits together

    const size_t off = (size_t)row * D_DIM + (size_t)lane * EPT;

    // 4 independent 16B loads (64B per thread, contiguous)
    const float4* __restrict__ xp = (const float4*)(x + off);
    const float4 va = xp[0];
    const float4 vb = xp[1];
    const float4 vc = xp[2];
    const float4 vd = xp[3];

    float e[EPT];
    e[0]  = va.x; e[1]  = va.y; e[2]  = va.z; e[3]  = va.w;
    e[4]  = vb.x; e[5]  = vb.y; e[6]  = vb.z; e[7]  = vb.w;
    e[8]  = vc.x; e[9]  = vc.y; e[10] = vc.z; e[11] = vc.w;
    e[12] = vd.x; e[13] = vd.y; e[14] = vd.z; e[15] = vd.w;

    // thread-local suffix sums of squares: ls[k] = sum_{j>=k} e[j]^2
    float ls[EPT];
    ls[EPT - 1] = e[EPT - 1] * e[EPT - 1];
#pragma unroll
    for (int k = EPT - 2; k >= 0; --k) ls[k] = fmaf(e[k], e[k], ls[k + 1]);

    // wave-level inclusive suffix scan of the per-thread totals
    float tot = ls[0];
#pragma unroll
    for (int o = 1; o < 64; o <<= 1) {
        float n = __shfl_down(tot, o, 64);
        if (lane + o < 64) tot += n;
    }
    const float incl = tot;           // suffix[16t] = sum_{k>=16t} x[k]^2
    const float excl = incl - ls[0];  // sum strictly after this thread's chunk

    // previous lane's last element: x[16t-1]
    const float xprev = __shfl_up(e[EPT - 1], 1, 64);

    float og[EPT];
    if (lane == 0) {
        og[0] = sqrtf(incl);                              // r -> out[0]
    } else {
        // phi[16t-1]: suffix[16t-1] = x[16t-1]^2 + suffix[16t]
        og[0] = ang(xprev, fmaf(xprev, xprev, incl));
    }
#pragma unroll
    for (int m = 1; m < EPT; ++m) {
        // out[16t+m] = phi[16t+m-1] = acos(e[m-1]/sqrt(ls[m-1]+excl))
        og[m] = ang(e[m - 1], ls[m - 1] + excl);
    }
    if (lane == 63 && e[EPT - 1] < 0.0f) {
        // out[D-1]: sign-adjusted phi[D-2]
        og[EPT - 1] = 6.283185307179586476f - og[EPT - 1];
    }

    // streaming (nontemporal) coalesced stores, 64B per thread
    v4f* __restrict__ op = (v4f*)(out + off);
    v4f t0 = {og[0],  og[1],  og[2],  og[3]};
    v4f t1 = {og[4],  og[5],  og[6],  og[7]};
    v4f t2 = {og[8],  og[9],  og[10], og[11]};
    v4f t3 = {og[12], og[13], og[14], og[15]};
    __builtin_nontemporal_store(t0, op + 0);
    __builtin_nontemporal_store(t1, op + 1);
    __builtin_nontemporal_store(t2, op + 2);
    __builtin_nontemporal_store(t3, op + 3);
}

extern "C" void kernel_launch(void* const* d_in, const int* in_sizes, int n_in,
                              void* d_out, int out_size, void* d_ws, size_t ws_size,
                              hipStream_t stream) {
    const float* x = (const float*)d_in[0];
    float* out = (float*)d_out;
    const int B = in_sizes[0] / D_DIM;  // 65536
    const int grid = (B + RPB - 1) / RPB;
    tohypersphere_kernel<<<grid, TPB, 0, stream>>>(x, out, B);
}

// Round 2
// 437.873 us; speedup vs baseline: 1.2366x; 1.2366x over previous
//
#include <hip/hip_runtime.h>
#include <math.h>

// ToHyperSphere: x (B=65536, D=1024) fp32 -> out (B, D) fp32
// out[0]   = sqrt(sum x^2)                        (r)
// out[j]   = acos(x[j-1]/suffix_norm[j-1]), j=1..D-2
// out[D-1] = x[D-1] < 0 ? 2pi - phi[D-2] : phi[D-2]
// suffix_norm[j] = sqrt(sum_{k>=j} x[k]^2)
//
// ONE WAVE PER ROW, GROUP-STRIDED LAYOUT (fixes round-1 coalescing bug):
// thread element (k, lane, j) = 256*k + 4*lane + j,  k=0..3, j=0..3.
// Each of the 4 load/store float4 instructions covers a CONTIGUOUS 1KB
// span per wave (full 64B lines) -- round 1's contiguous-per-thread
// layout made every instruction 64B-strided across lanes, causing 1.8x
// HBM write amplification (partial-line NT writes) and 2.4 TB/s BW.
//  - suffix scan: per-group 3-FMA local scan + 4 independent 6-step
//    __shfl_down wave scans; cross-group offsets via lane-0 broadcast.
//    No LDS, no __syncthreads.
//  - NT stores (full-line now): output is write-only in the timed loop;
//    don't evict the input from L2/L3.

#define D_DIM 1024
#define TPB 256       // 4 waves per block
#define RPB 4         // rows per block (one per wave)
#define NG 4          // groups per row (each 256 elems = 64 lanes x 4)

typedef float v4f __attribute__((ext_vector_type(4)));

__device__ __forceinline__ float ang(float num, float den) {
    float r = num * rsqrtf(den);
    r = fminf(1.0f, fmaxf(-1.0f, r));
    return acosf(r);
}

__global__ __launch_bounds__(TPB) void tohypersphere_kernel(
    const float* __restrict__ x, float* __restrict__ out, int n_rows) {
    const int lane = threadIdx.x & 63;
    const int wv   = threadIdx.x >> 6;
    const int row  = blockIdx.x * RPB + wv;
    if (row >= n_rows) return;  // whole wave exits together

    const float4* __restrict__ xp = (const float4*)(x + (size_t)row * D_DIM);

    // 4 independent, per-instruction-contiguous 16B loads
    float4 v[NG];
#pragma unroll
    for (int k = 0; k < NG; ++k) v[k] = xp[64 * k + lane];

    // per-group thread-local suffix sums of squares
    // s0[k] = sum of all 4, s1/s2/s3 = suffixes within the chunk
    float s0[NG], s1[NG], s2[NG], s3[NG];
#pragma unroll
    for (int k = 0; k < NG; ++k) {
        s3[k] = v[k].w * v[k].w;
        s2[k] = fmaf(v[k].z, v[k].z, s3[k]);
        s1[k] = fmaf(v[k].y, v[k].y, s2[k]);
        s0[k] = fmaf(v[k].x, v[k].x, s1[k]);
    }

    // 4 independent wave-level inclusive suffix scans (interleaved for ILP)
    float tot[NG];
#pragma unroll
    for (int k = 0; k < NG; ++k) tot[k] = s0[k];
#pragma unroll
    for (int o = 1; o < 64; o <<= 1) {
#pragma unroll
        for (int k = 0; k < NG; ++k) {
            float n = __shfl_down(tot[k], o, 64);
            if (lane + o < 64) tot[k] += n;
        }
    }

    // group totals = lane 0's inclusive value, broadcast to all lanes
    float G[NG];
#pragma unroll
    for (int k = 0; k < NG; ++k) G[k] = __shfl(tot[k], 0, 64);

    // base[k] = (sum over lanes > lane within group k) + (sum of groups > k)
    float base[NG];
    float after = 0.0f;
#pragma unroll
    for (int k = NG - 1; k >= 0; --k) {
        base[k] = (tot[k] - s0[k]) + after;
        after += G[k];
    }

    // boundary element x[p0-1]:
    //   lane>0 : previous lane's last elem of same group
    //   lane==0: lane 63's last elem of group k-1 (k=0,lane=0 is the r branch)
    float xup[NG], xpg[NG];
#pragma unroll
    for (int k = 0; k < NG; ++k) xup[k] = __shfl_up(v[k].w, 1, 64);
#pragma unroll
    for (int k = 0; k < NG; ++k) xpg[k] = __shfl(v[(k + NG - 1) % NG].w, 63, 64);

    v4f* __restrict__ op = (v4f*)(out + (size_t)row * D_DIM);
#pragma unroll
    for (int k = 0; k < NG; ++k) {
        const float suf0 = s0[k] + base[k];
        float o0, o1, o2, o3;
        if (k == 0 && lane == 0) {
            o0 = sqrtf(suf0);  // r -> out[0] (suf0 here = full row sum)
        } else {
            const float xprev = (lane == 0) ? xpg[k] : xup[k];
            // phi[p0-1]: suffix[p0-1] = x[p0-1]^2 + suffix[p0]
            o0 = ang(xprev, fmaf(xprev, xprev, suf0));
        }
        o1 = ang(v[k].x, suf0);             // phi[p0]   -> out[p0+1]
        o2 = ang(v[k].y, s1[k] + base[k]);  // phi[p0+1] -> out[p0+2]
        o3 = ang(v[k].z, s2[k] + base[k]);  // phi[p0+2] -> out[p0+3]
        if (k == NG - 1 && lane == 63 && v[k].w < 0.0f) {
            // out[D-1]: sign-adjusted phi[D-2]
            o3 = 6.283185307179586476f - o3;
        }
        v4f t = {o0, o1, o2, o3};
        __builtin_nontemporal_store(t, op + 64 * k + lane);
    }
}

extern "C" void kernel_launch(void* const* d_in, const int* in_sizes, int n_in,
                              void* d_out, int out_size, void* d_ws, size_t ws_size,
                              hipStream_t stream) {
    const float* x = (const float*)d_in[0];
    float* out = (float*)d_out;
    const int B = in_sizes[0] / D_DIM;  // 65536
    const int grid = (B + RPB - 1) / RPB;
    tohypersphere_kernel<<<grid, TPB, 0, stream>>>(x, out, B);
}

// Round 3
// 425.234 us; speedup vs baseline: 1.2734x; 1.0297x over previous
//
#include <hip/hip_runtime.h>
#include <math.h>

// ToHyperSphere: x (B=65536, D=1024) fp32 -> out (B, D) fp32
// out[0]   = sqrt(sum x^2)                        (r)
// out[j]   = acos(x[j-1]/suffix_norm[j-1]), j=1..D-2
// out[D-1] = x[D-1] < 0 ? 2pi - phi[D-2] : phi[D-2]
// suffix_norm[j] = sqrt(sum_{k>=j} x[k]^2)
//
// ONE WAVE PER ROW, GROUP-STRIDED LAYOUT:
// thread element (k, lane, j) = 256*k + 4*lane + j, k=0..3, j=0..3.
// Every load/store instruction covers a contiguous 1KB span per wave.
//
// Round-3 changes (round 2 was ~155us/dispatch, only ~2.6 TB/s -- NOT
// memory-bound; limiter = cross-lane scan overhead + libm acos):
//  - suffix scan via DPP row_shl:{1,2,4,8} bound_ctrl:0 (4 unguarded
//    v_add per group, full-rate VALU, no LDS-pipe ds_bpermute, no
//    cmp/cndmask guards) + v_readlane row/group total combine.
//    Round 2 paid 24 ds_bpermute + 24 guard pairs per thread.
//  - polynomial acos (A&S 4.4.46: 7 FMA + sqrt + select, |err|~1e-6
//    vs 7.8e-3 tolerance) instead of libm acosf (~25 ops + branches).
//  - regular stores (NT reverted: round 0 with cached stores was faster;
//    fills hit 6.5 TB/s with cached stores).

#define D_DIM 1024
#define TPB 256       // 4 waves per block
#define RPB 4         // rows per block (one per wave)
#define NG 4          // groups per row (each 256 elems = 64 lanes x 4)

typedef float v4f __attribute__((ext_vector_type(4)));

// DPP helper: value of (lane + N) within the 16-lane row, 0 if out of row.
template <int CTRL>
__device__ __forceinline__ float dpp0(float x) {
    return __builtin_bit_cast(
        float, __builtin_amdgcn_update_dpp(0, __builtin_bit_cast(int, x),
                                           CTRL, 0xF, 0xF, true));
}

__device__ __forceinline__ float rdlane(float x, int l) {
    return __builtin_bit_cast(
        float, __builtin_amdgcn_readlane(__builtin_bit_cast(int, x), l));
}

// acos via Abramowitz&Stegun 4.4.46: acos(a) = sqrt(1-a)*poly(a), a in [0,1];
// acos(x) = pi - acos(-x) for x < 0. |err| <= ~2e-8 (poly) ~1e-6 (fp32).
__device__ __forceinline__ float fast_acos(float x) {
    float a = fabsf(x);
    float p = fmaf(a, -0.0012624911f, 0.0066700901f);
    p = fmaf(p, a, -0.0170881256f);
    p = fmaf(p, a, 0.0308918810f);
    p = fmaf(p, a, -0.0501743046f);
    p = fmaf(p, a, 0.0889789874f);
    p = fmaf(p, a, -0.2145988016f);
    p = fmaf(p, a, 1.5707963050f);
    float r = sqrtf(1.0f - a) * p;
    return x < 0.0f ? 3.14159274101257f - r : r;
}

__device__ __forceinline__ float ang(float num, float den) {
    float r = num * rsqrtf(den);
    r = fminf(1.0f, fmaxf(-1.0f, r));
    return fast_acos(r);
}

__global__ __launch_bounds__(TPB) void tohypersphere_kernel(
    const float* __restrict__ x, float* __restrict__ out, int n_rows) {
    const int lane = threadIdx.x & 63;
    const int wv   = threadIdx.x >> 6;
    const int row  = blockIdx.x * RPB + wv;
    if (row >= n_rows) return;  // whole wave exits together

    const float4* __restrict__ xp = (const float4*)(x + (size_t)row * D_DIM);

    // 4 independent, per-instruction-contiguous 16B loads
    float4 v[NG];
#pragma unroll
    for (int k = 0; k < NG; ++k) v[k] = xp[64 * k + lane];

    // per-chunk thread-local suffix sums of squares
    float s0[NG], s1[NG], s2[NG];
#pragma unroll
    for (int k = 0; k < NG; ++k) {
        float s3 = v[k].w * v[k].w;
        s2[k] = fmaf(v[k].z, v[k].z, s3);
        s1[k] = fmaf(v[k].y, v[k].y, s2[k]);
        s0[k] = fmaf(v[k].x, v[k].x, s1[k]);
    }

    // within-row (16-lane) inclusive suffix scan, 4 groups interleaved.
    // row_shl:N pulls from lane+N (bound_ctrl -> 0 past row end).
    float ts[NG];
#pragma unroll
    for (int k = 0; k < NG; ++k) ts[k] = s0[k];
#pragma unroll
    for (int k = 0; k < NG; ++k) ts[k] += dpp0<0x101>(ts[k]);  // +1
#pragma unroll
    for (int k = 0; k < NG; ++k) ts[k] += dpp0<0x102>(ts[k]);  // +2
#pragma unroll
    for (int k = 0; k < NG; ++k) ts[k] += dpp0<0x104>(ts[k]);  // +4
#pragma unroll
    for (int k = 0; k < NG; ++k) ts[k] += dpp0<0x108>(ts[k]);  // +8

    // row totals (at lanes 0,16,32,48) -> wave-uniform scalars
    float R[NG][4];
#pragma unroll
    for (int k = 0; k < NG; ++k) {
        R[k][0] = rdlane(ts[k], 0);
        R[k][1] = rdlane(ts[k], 16);
        R[k][2] = rdlane(ts[k], 32);
        R[k][3] = rdlane(ts[k], 48);
    }
    const int r16 = lane >> 4;

    // group totals and suffix-of-groups
    float G[NG];
#pragma unroll
    for (int k = 0; k < NG; ++k) G[k] = (R[k][0] + R[k][1]) + (R[k][2] + R[k][3]);
    float ag[NG];  // sum of groups strictly after k
    ag[NG - 1] = 0.0f;
#pragma unroll
    for (int k = NG - 2; k >= 0; --k) ag[k] = ag[k + 1] + G[k + 1];

    // base[k] = suffix strictly after this thread's chunk in group k
    float base[NG];
#pragma unroll
    for (int k = 0; k < NG; ++k) {
        float af = 0.0f;  // rows after this thread's row, same group
        if (r16 < 1) af += R[k][1];
        if (r16 < 2) af += R[k][2];
        if (r16 < 3) af += R[k][3];
        base[k] = (ts[k] - s0[k]) + af + ag[k];
    }

    // boundary element x[p0-1]
    float xup[NG], xpg[NG];
#pragma unroll
    for (int k = 0; k < NG; ++k) xup[k] = __shfl_up(v[k].w, 1, 64);
#pragma unroll
    for (int k = 0; k < NG; ++k) xpg[k] = rdlane(v[(k + NG - 1) % NG].w, 63);

    v4f* __restrict__ op = (v4f*)(out + (size_t)row * D_DIM);
#pragma unroll
    for (int k = 0; k < NG; ++k) {
        const float suf0 = s0[k] + base[k];
        float o0, o1, o2, o3;
        if (k == 0 && lane == 0) {
            o0 = sqrtf(suf0);  // r -> out[0] (suf0 = full row sum)
        } else {
            const float xprev = (lane == 0) ? xpg[k] : xup[k];
            // phi[p0-1]: suffix[p0-1] = x[p0-1]^2 + suffix[p0]
            o0 = ang(xprev, fmaf(xprev, xprev, suf0));
        }
        o1 = ang(v[k].x, suf0);             // phi[p0]   -> out[p0+1]
        o2 = ang(v[k].y, s1[k] + base[k]);  // phi[p0+1] -> out[p0+2]
        o3 = ang(v[k].z, s2[k] + base[k]);  // phi[p0+2] -> out[p0+3]
        if (k == NG - 1 && lane == 63 && v[k].w < 0.0f) {
            // out[D-1]: sign-adjusted phi[D-2]
            o3 = 6.283185307179586476f - o3;
        }
        v4f t = {o0, o1, o2, o3};
        op[64 * k + lane] = t;
    }
}

extern "C" void kernel_launch(void* const* d_in, const int* in_sizes, int n_in,
                              void* d_out, int out_size, void* d_ws, size_t ws_size,
                              hipStream_t stream) {
    const float* x = (const float*)d_in[0];
    float* out = (float*)d_out;
    const int B = in_sizes[0] / D_DIM;  // 65536
    const int grid = (B + RPB - 1) / RPB;
    tohypersphere_kernel<<<grid, TPB, 0, stream>>>(x, out, B);
}

// Round 4
// 411.947 us; speedup vs baseline: 1.3144x; 1.0323x over previous
//
#include <hip/hip_runtime.h>
#include <math.h>

// ToHyperSphere: x (B=65536, D=1024) fp32 -> out (B, D) fp32
// out[0]   = sqrt(sum x^2)                        (r)
// out[j]   = acos(x[j-1]/suffix_norm[j-1]), j=1..D-2
// out[D-1] = x[D-1] < 0 ? 2pi - phi[D-2] : phi[D-2]
// suffix_norm[j] = sqrt(sum_{k>=j} x[k]^2)
//
// ROUND-4: best measured structure (round 0: block-per-row, 1 float4 per
// thread, est. 127us) + the round-3 VALU cuts that were proven in the
// wrong structure (wave-per-row, est. 142us):
//  - DPP suffix scan: 4 unguarded v_add via row_shl:{1,2,4,8} bound_ctrl:0
//    + v_readlane row-total combine. Replaces 6 guarded __shfl_down steps
//    (6 ds_bpermute + 6 cmp/cndmask through the LDS pipe).
//  - polynomial acos (A&S 4.4.46, 7 FMA + sqrt + select; absmax was
//    unchanged at 0.0078125 in round 3) instead of libm acosf.
//  - one __syncthreads, 8 floats of LDS for cross-wave totals + edge elem.
// Per-thread: 1 float4 load, ~90 VALU, 1 float4 store. All accesses
// per-instruction contiguous (1KB/wave).

#define D_DIM 1024
#define TPB 256  // 4 waves per block, one block per row

typedef float v4f __attribute__((ext_vector_type(4)));

// DPP: value of (lane + N) within the 16-lane row, 0 past row end.
template <int CTRL>
__device__ __forceinline__ float dpp0(float x) {
    return __builtin_bit_cast(
        float, __builtin_amdgcn_update_dpp(0, __builtin_bit_cast(int, x),
                                           CTRL, 0xF, 0xF, true));
}

__device__ __forceinline__ float rdlane(float x, int l) {
    return __builtin_bit_cast(
        float, __builtin_amdgcn_readlane(__builtin_bit_cast(int, x), l));
}

// acos via Abramowitz&Stegun 4.4.46: acos(a) = sqrt(1-a)*poly(a), a in [0,1];
// acos(x) = pi - acos(-x) for x < 0.
__device__ __forceinline__ float fast_acos(float x) {
    float a = fabsf(x);
    float p = fmaf(a, -0.0012624911f, 0.0066700901f);
    p = fmaf(p, a, -0.0170881256f);
    p = fmaf(p, a, 0.0308918810f);
    p = fmaf(p, a, -0.0501743046f);
    p = fmaf(p, a, 0.0889789874f);
    p = fmaf(p, a, -0.2145988016f);
    p = fmaf(p, a, 1.5707963050f);
    float r = sqrtf(1.0f - a) * p;
    return x < 0.0f ? 3.14159274101257f - r : r;
}

__device__ __forceinline__ float ang(float num, float den) {
    float r = num * rsqrtf(den);
    r = fminf(1.0f, fmaxf(-1.0f, r));
    return fast_acos(r);
}

__global__ __launch_bounds__(TPB) void tohypersphere_kernel(
    const float* __restrict__ x, float* __restrict__ out) {
    const int t = threadIdx.x;
    const int lane = t & 63;
    const int wave = t >> 6;
    const int r16 = lane >> 4;
    const size_t row_off = (size_t)blockIdx.x * D_DIM;

    const float4 v = ((const float4*)(x + row_off))[t];

    // thread-local suffix sums of squares (elements 4t..4t+3)
    const float s3 = v.w * v.w;
    const float s2 = fmaf(v.z, v.z, s3);
    const float s1 = fmaf(v.y, v.y, s2);
    const float s0 = fmaf(v.x, v.x, s1);

    // 16-lane-row inclusive suffix scan of s0 (unguarded DPP adds)
    float ts = s0;
    ts += dpp0<0x101>(ts);  // row_shl:1
    ts += dpp0<0x102>(ts);  // row_shl:2
    ts += dpp0<0x104>(ts);  // row_shl:4
    ts += dpp0<0x108>(ts);  // row_shl:8

    // row totals live at lanes 0,16,32,48 -> wave-uniform scalars
    const float R0 = rdlane(ts, 0);
    const float R1 = rdlane(ts, 16);
    const float R2 = rdlane(ts, 32);
    const float R3 = rdlane(ts, 48);

    // inclusive suffix within the wave
    float after_rows = 0.0f;
    if (r16 < 1) after_rows += R1;
    if (r16 < 2) after_rows += R2;
    if (r16 < 3) after_rows += R3;
    const float incl_wave = ts + after_rows;
    const float wtot = (R0 + R1) + (R2 + R3);  // wave total (uniform)

    __shared__ float wave_tot[4];  // per-wave sum of squares
    __shared__ float edge_xw[4];   // last element (v.w) of each wave
    if (lane == 0) wave_tot[wave] = wtot;
    if (lane == 63) edge_xw[wave] = v.w;

    // previous thread's last element x[4t-1] (intra-wave part, pre-barrier)
    float xw_prev = __shfl_up(v.w, 1, 64);

    __syncthreads();

    float after_waves = 0.0f;
#pragma unroll
    for (int w = 1; w < 4; ++w)
        if (w > wave) after_waves += wave_tot[w];
    if (lane == 0 && wave > 0) xw_prev = edge_xw[wave - 1];

    const float incl = incl_wave + after_waves;  // suffix[4t]
    const float excl = incl - s0;                // suffix strictly after 4t+3

    float o0, o1, o2, o3;
    o1 = ang(v.x, incl);       // phi[4t]   -> out[4t+1]
    o2 = ang(v.y, s1 + excl);  // phi[4t+1] -> out[4t+2]
    o3 = ang(v.z, s2 + excl);  // phi[4t+2] -> out[4t+3]
    if (t == 0) {
        o0 = sqrtf(incl);      // r -> out[0]
    } else {
        // phi[4t-1]: suffix[4t-1] = x[4t-1]^2 + suffix[4t]
        o0 = ang(xw_prev, fmaf(xw_prev, xw_prev, incl));
    }
    if (t == TPB - 1 && v.w < 0.0f) {
        // out[D-1]: sign-adjusted phi[D-2]
        o3 = 6.283185307179586476f - o3;
    }

    v4f tv = {o0, o1, o2, o3};
    ((v4f*)(out + row_off))[t] = tv;
}

extern "C" void kernel_launch(void* const* d_in, const int* in_sizes, int n_in,
                              void* d_out, int out_size, void* d_ws, size_t ws_size,
                              hipStream_t stream) {
    const float* x = (const float*)d_in[0];
    float* out = (float*)d_out;
    const int B = in_sizes[0] / D_DIM;  // 65536
    tohypersphere_kernel<<<B, TPB, 0, stream>>>(x, out);
}